// Round 10
// baseline (1020.912 us; speedup 1.0000x reference)
//
#include <hip/hip_runtime.h>

#define B_ 16
#define N_ 512
#define F_ 512
#define H_ 16
#define DH_ 32
#define HID_ 2048
#define L_ 6
#define QKV_LD 1536
#define NEGINF -1e9f
#define NEGBF 0xCE6Eu   // bf16(-1e9)
#define ONEBF 0x3F80    // bf16(1.0)

typedef short short8 __attribute__((ext_vector_type(8)));
typedef float f32x4 __attribute__((ext_vector_type(4)));

__device__ __forceinline__ unsigned short f2bf(float f) {
  unsigned int u = __float_as_uint(f);
  unsigned int r = (u + 0x7fff + ((u >> 16) & 1)) >> 16;
  return (unsigned short)r;
}
__device__ __forceinline__ float bf2f(unsigned short v) {
  return __uint_as_float(((unsigned int)v) << 16);
}

// ------------------------------------------------ weight transpose+convert
__global__ __launch_bounds__(256) void tconv4_kernel(
    const float* __restrict__ Wq, const float* __restrict__ Wk,
    const float* __restrict__ Wv, const float* __restrict__ Wo,
    unsigned short* __restrict__ dq, unsigned short* __restrict__ do_)
{
  __shared__ float tile[32][33];
  const int wi = blockIdx.z & 3, l = blockIdx.z >> 2;
  const float* s =
      ((wi == 0) ? Wq : (wi == 1) ? Wk : (wi == 2) ? Wv : Wo) + (size_t)l * F_ * F_;
  unsigned short* d = (wi < 3)
      ? dq + (size_t)l * QKV_LD * F_ + (size_t)wi * 512 * F_
      : do_ + (size_t)l * F_ * F_;
  const int n0 = blockIdx.x * 32, k0 = blockIdx.y * 32;
  const int tx = threadIdx.x, ty = threadIdx.y;   // 32x8
#pragma unroll
  for (int i = 0; i < 4; ++i)
    tile[ty + 8 * i][tx] = s[(size_t)(k0 + ty + 8 * i) * F_ + n0 + tx];
  __syncthreads();
#pragma unroll
  for (int i = 0; i < 4; ++i)
    d[(size_t)(n0 + ty + 8 * i) * F_ + k0 + tx] = f2bf(tile[tx][ty + 8 * i]);
}

__global__ __launch_bounds__(256) void tconv_kernel(
    const float* __restrict__ src, unsigned short* __restrict__ dst,
    int K, int N, size_t src_stride_z, size_t dst_stride_z, size_t dst_off)
{
  __shared__ float tile[32][33];
  const int n0 = blockIdx.x * 32, k0 = blockIdx.y * 32;
  const int tx = threadIdx.x, ty = threadIdx.y;   // 32x8
  const float* s = src + blockIdx.z * src_stride_z;
  unsigned short* d = dst + blockIdx.z * dst_stride_z + dst_off;
#pragma unroll
  for (int i = 0; i < 4; ++i)
    tile[ty + 8 * i][tx] = s[(size_t)(k0 + ty + 8 * i) * N + n0 + tx];
  __syncthreads();
#pragma unroll
  for (int i = 0; i < 4; ++i)
    d[(size_t)(n0 + ty + 8 * i) * K + k0 + tx] = f2bf(tile[tx][ty + 8 * i]);
}

__global__ __launch_bounds__(256) void biasqkv_kernel(
    const float* __restrict__ bq, const float* __restrict__ bk,
    const float* __restrict__ bv, float* __restrict__ dst)
{
  int i = blockIdx.x * 256 + threadIdx.x;
  if (i >= L_ * QKV_LD) return;
  int l = i / QKV_LD, j = i % QKV_LD;
  float v = (j < 512) ? bq[l * 512 + j]
          : (j < 1024) ? bk[l * 512 + j - 512] : bv[l * 512 + j - 1024];
  dst[i] = v;
}

// --------------------------------------------- packed dist+mask code table
__global__ __launch_bounds__(256) void packcode_kernel(
    const int* __restrict__ dist, const int* __restrict__ num_nodes,
    unsigned char* __restrict__ code)
{
  int g = blockIdx.x * 256 + threadIdx.x;   // one uchar4 per thread
  int j4 = (g & 127) << 2;
  int bn = g >> 7;
  int b = bn >> 9, i = bn & 511;
  int nn = num_nodes[b];
  int4 d = *(const int4*)(dist + (size_t)bn * N_ + j4);
  bool rinv = i >= nn;
  unsigned char c0 = (j4     >= nn || (rinv && (j4    ) >= 1)) ? 12 : (unsigned char)d.x;
  unsigned char c1 = (j4 + 1 >= nn || (rinv && (j4 + 1) >= 1)) ? 12 : (unsigned char)d.y;
  unsigned char c2 = (j4 + 2 >= nn || (rinv && (j4 + 2) >= 1)) ? 12 : (unsigned char)d.z;
  unsigned char c3 = (j4 + 3 >= nn || (rinv && (j4 + 3) >= 1)) ? 12 : (unsigned char)d.w;
  unsigned int packed = (unsigned int)c0 | ((unsigned int)c1 << 8) |
                        ((unsigned int)c2 << 16) | ((unsigned int)c3 << 24);
  *(unsigned int*)(code + (size_t)bn * N_ + j4) = packed;
}

// ---------------------------------------------------------------- embed
__global__ __launch_bounds__(256) void embed_kernel(
    const float* __restrict__ nfeats, const int* __restrict__ degrees,
    const int* __restrict__ num_nodes, const float* __restrict__ din,
    const float* __restrict__ dout, float* __restrict__ x,
    unsigned short* __restrict__ xb)
{
  int g = blockIdx.x * 256 + threadIdx.x;
  int bn = g >> 7;
  int f  = (g & 127) << 2;
  int b  = bn >> 9;
  int n  = bn & 511;
  int nn = num_nodes[b];
  float4 r = {0.f, 0.f, 0.f, 0.f};
  if (n < nn) {
    int deg = degrees[bn];
    deg = deg < 0 ? 0 : (deg > 100 ? 100 : deg);
    float4 a = *(const float4*)(nfeats + (size_t)bn * F_ + f);
    float4 c = *(const float4*)(din + (size_t)deg * F_ + f);
    float4 e = *(const float4*)(dout + (size_t)deg * F_ + f);
    r.x = a.x + c.x + e.x; r.y = a.y + c.y + e.y;
    r.z = a.z + c.z + e.z; r.w = a.w + c.w + e.w;
  }
  *(float4*)(x + (size_t)bn * F_ + f) = r;
  unsigned short* xbp = xb + (size_t)bn * F_ + f;
  xbp[0] = f2bf(r.x); xbp[1] = f2bf(r.y); xbp[2] = f2bf(r.z); xbp[3] = f2bf(r.w);
}

// ------------------------------------------------------- bf16 MFMA GEMM (128x128)
__global__ __launch_bounds__(256) void mfma_gemm_kernel(
    const unsigned short* __restrict__ A, const unsigned short* __restrict__ Bt,
    const float* __restrict__ bias, float* __restrict__ Cf,
    unsigned short* __restrict__ Cb, unsigned short* __restrict__ vt,
    int K, int Nout, float scale, int epi,
    const int* __restrict__ num_nodes)
{
  const int m0 = blockIdx.x * 128;
  {
    const int bb = m0 >> 9;
    const int nnr = (num_nodes[bb] + 127) & ~127;
    if ((m0 & 511) >= nnr) return;
  }

  __shared__ unsigned short SM[4][4096];   // [0..1]=As bufs, [2..3]=Bs bufs (32 KB)

  const int t  = threadIdx.x;
  const int n0 = blockIdx.y * 128;

  const unsigned short* Ab = A  + (size_t)(m0 + (t >> 2)) * K + (t & 3) * 8;
  const unsigned short* Bb = Bt + (size_t)(n0 + (t >> 2)) * K + (t & 3) * 8;
  const size_t rowskip = (size_t)64 * K;
  const int lo = t * 8;

  const int lane = t & 63, w = t >> 6;
  const int wm = (w & 1) * 64, wn = (w >> 1) * 64;
  const int fr = lane & 15;
  const int fk = (lane >> 4) * 8;

  short8 ar0, ar1, br0, br1;
#define LOADT(K0)                                        \
  {                                                      \
    ar0 = *(const short8*)(Ab + (K0));                   \
    ar1 = *(const short8*)(Ab + rowskip + (K0));         \
    br0 = *(const short8*)(Bb + (K0));                   \
    br1 = *(const short8*)(Bb + rowskip + (K0));         \
  }
#define STORET(BUF)                                      \
  {                                                      \
    *(short8*)&SM[BUF][lo]            = ar0;             \
    *(short8*)&SM[BUF][lo + 2048]     = ar1;             \
    *(short8*)&SM[2 + (BUF)][lo]        = br0;           \
    *(short8*)&SM[2 + (BUF)][lo + 2048] = br1;           \
  }

  f32x4 acc[4][4];
#pragma unroll
  for (int i = 0; i < 4; ++i)
#pragma unroll
    for (int j = 0; j < 4; ++j) acc[i][j] = (f32x4){0.f, 0.f, 0.f, 0.f};

  LOADT(0)
  STORET(0)
  LOADT(32)

  int buf = 0;
  for (int k0 = 0; k0 < K; k0 += 32, buf ^= 1) {
    __syncthreads();
    if (k0 + 32 < K) {
      STORET(buf ^ 1)
      if (k0 + 64 < K) LOADT(k0 + 64)
    }

    short8 af[4], bf[4];
#pragma unroll
    for (int mi = 0; mi < 4; ++mi)
      af[mi] = *(const short8*)&SM[buf][(wm + mi * 16 + fr) * 32 + fk];
#pragma unroll
    for (int ni = 0; ni < 4; ++ni)
      bf[ni] = *(const short8*)&SM[2 + buf][(wn + ni * 16 + fr) * 32 + fk];
#pragma unroll
    for (int mi = 0; mi < 4; ++mi)
#pragma unroll
      for (int ni = 0; ni < 4; ++ni)
        acc[mi][ni] = __builtin_amdgcn_mfma_f32_16x16x32_bf16(
            af[mi], bf[ni], acc[mi][ni], 0, 0, 0);
  }
#undef LOADT
#undef STORET

  const int er = (lane >> 4) * 4;
  const int ec = lane & 15;

  if (epi == 2 && n0 >= 1024) {
    // ---- V block: restage tile through LDS, coalesced vt out
    unsigned long long* SMu = (unsigned long long*)&SM[0][0];
    __syncthreads();
#pragma unroll
    for (int mi = 0; mi < 4; ++mi) {
#pragma unroll
      for (int ni = 0; ni < 4; ++ni) {
        int d  = wn + ni * 16 + ec;
        int jg = (wm + mi * 16 + er) >> 2;
        float bv = bias[n0 + d];
        unsigned short pk[4];
#pragma unroll
        for (int r = 0; r < 4; ++r) pk[r] = f2bf(acc[mi][ni][r] + bv);
        SMu[d * 32 + (jg ^ (d & 31))] = *(unsigned long long*)pk;
      }
    }
    __syncthreads();
    const int d = t >> 1, half = t & 1;
    const int bb = m0 >> 9, j0t = m0 & 511;
    unsigned short* vrow =
        vt + ((size_t)(bb * 512 + (n0 - 1024) + d)) * 512 + j0t + half * 64;
#pragma unroll
    for (int k = 0; k < 8; ++k) {
      int g0 = half * 16 + 2 * k;
      unsigned long long v2[2];
      v2[0] = SMu[d * 32 + (g0 ^ (d & 31))];
      v2[1] = SMu[d * 32 + ((g0 + 1) ^ (d & 31))];
      *(short8*)(vrow + k * 8) = *(short8*)v2;
    }
    return;
  }

#pragma unroll
  for (int mi = 0; mi < 4; ++mi) {
#pragma unroll
    for (int ni = 0; ni < 4; ++ni) {
      int gm = m0 + wm + mi * 16 + er;
      int gn = n0 + wn + ni * 16 + ec;
      float bv = bias[gn];
#pragma unroll
      for (int r = 0; r < 4; ++r) {
        float v = acc[mi][ni][r] + bv;
        if (epi == 1) v = fmaxf(v, 0.f);
        else if (epi == 2 && gn < 512) v *= scale;
        size_t off = (size_t)(gm + r) * Nout + gn;
        if (Cf) Cf[off] = v;
        if (Cb) Cb[off] = f2bf(v);
      }
    }
  }
}

// --------------------------------------------- bf16 MFMA GEMM (64x128 tile)
__global__ __launch_bounds__(256) void mfma_gemm64_kernel(
    const unsigned short* __restrict__ A, const unsigned short* __restrict__ Bt,
    const float* __restrict__ bias, unsigned short* __restrict__ Cb,
    int K, int Nout, const int* __restrict__ num_nodes)
{
  const int m0 = blockIdx.x * 64;
  {
    const int bb = m0 >> 9;
    const int nnr = (num_nodes[bb] + 127) & ~127;
    if ((m0 & 511) >= nnr) return;
  }

  __shared__ unsigned short As[2][64 * 32];
  __shared__ unsigned short Bs[2][128 * 32];

  const int t  = threadIdx.x;
  const int n0 = blockIdx.y * 128;

  const unsigned short* Ab = A  + (size_t)(m0 + (t >> 2)) * K + (t & 3) * 8;
  const unsigned short* Bb = Bt + (size_t)(n0 + (t >> 2)) * K + (t & 3) * 8;
  const size_t rowskip = (size_t)64 * K;
  const int lo = t * 8;

  const int lane = t & 63, w = t >> 6;
  const int wm = (w & 1) * 32, wn = (w >> 1) * 64;
  const int fr = lane & 15;
  const int fk = (lane >> 4) * 8;

  short8 ar0, br0, br1;
#define LOADT(K0)                                        \
  {                                                      \
    ar0 = *(const short8*)(Ab + (K0));                   \
    br0 = *(const short8*)(Bb + (K0));                   \
    br1 = *(const short8*)(Bb + rowskip + (K0));         \
  }
#define STORET(BUF)                                      \
  {                                                      \
    *(short8*)&As[BUF][lo]        = ar0;                 \
    *(short8*)&Bs[BUF][lo]        = br0;                 \
    *(short8*)&Bs[BUF][lo + 2048] = br1;                 \
  }

  f32x4 acc[2][4];
#pragma unroll
  for (int i = 0; i < 2; ++i)
#pragma unroll
    for (int j = 0; j < 4; ++j) acc[i][j] = (f32x4){0.f, 0.f, 0.f, 0.f};

  LOADT(0)
  STORET(0)
  LOADT(32)

  int buf = 0;
  for (int k0 = 0; k0 < K; k0 += 32, buf ^= 1) {
    __syncthreads();
    if (k0 + 32 < K) {
      STORET(buf ^ 1)
      if (k0 + 64 < K) LOADT(k0 + 64)
    }

    short8 af[2], bf[4];
#pragma unroll
    for (int mi = 0; mi < 2; ++mi)
      af[mi] = *(const short8*)&As[buf][(wm + mi * 16 + fr) * 32 + fk];
#pragma unroll
    for (int ni = 0; ni < 4; ++ni)
      bf[ni] = *(const short8*)&Bs[buf][(wn + ni * 16 + fr) * 32 + fk];
#pragma unroll
    for (int mi = 0; mi < 2; ++mi)
#pragma unroll
      for (int ni = 0; ni < 4; ++ni)
        acc[mi][ni] = __builtin_amdgcn_mfma_f32_16x16x32_bf16(
            af[mi], bf[ni], acc[mi][ni], 0, 0, 0);
  }
#undef LOADT
#undef STORET

  const int er = (lane >> 4) * 4;
  const int ec = lane & 15;
#pragma unroll
  for (int mi = 0; mi < 2; ++mi) {
#pragma unroll
    for (int ni = 0; ni < 4; ++ni) {
      int gm = m0 + wm + mi * 16 + er;
      int gn = n0 + wn + ni * 16 + ec;
      float bv = bias[gn];
#pragma unroll
      for (int r = 0; r < 4; ++r)
        Cb[(size_t)(gm + r) * Nout + gn] = f2bf(acc[mi][ni][r] + bv);
    }
  }
}

// ---------------------------------------------- MFMA flash attention
// ZERO barriers: K/V/Q fragments loaded directly from global in MFMA
// fragment order (double-buffered, 2 chunks/iter); softmax is a plain sum
// (no online max) so waves are fully independent. Only LDS: per-wave,
// phase-double-buffered PB for the bias->P cross-lane transform
// (same-wave ds_write->ds_read without barrier: HW-verified pattern, R8/R9).
__global__ __launch_bounds__(256, 3) void attn_kernel(
    const unsigned short* __restrict__ qkv, const unsigned short* __restrict__ vtb,
    const unsigned char* __restrict__ code, const float* __restrict__ spatial_emb,
    const int* __restrict__ num_nodes, unsigned short* __restrict__ o)
{
  const int h  = blockIdx.x;
  const int i0 = blockIdx.y * 128;
  const int b  = blockIdx.z;
  const int nn = num_nodes[b];
  if (i0 >= ((nn + 127) & ~127)) return;     // dead q-tile
  const int t  = threadIdx.x;
  const int lane = t & 63, w = t >> 6;
  const int q4 = lane >> 4, c = lane & 15;

  __shared__ __align__(16) unsigned short PB[4][2][32][72];  // 36.9 KB
  __shared__ unsigned short sbxw[4][16];     // per-wave bias LUT (no barrier)

  if (lane < 16)
    sbxw[w][lane] = (lane < 12) ? f2bf(spatial_emb[lane * H_ + h])
                                : (unsigned short)NEGBF;

  // ---- Q fragments: direct global load (A-layout: row m= i0+w*32+mt*16+c)
  const unsigned short* qrow =
      qkv + (size_t)(b * N_ + i0 + w * 32 + c) * QKV_LD + h * DH_ + q4 * 8;
  short8 Qf[2];
  Qf[0] = *(const short8*)qrow;
  Qf[1] = *(const short8*)(qrow + (size_t)16 * QKV_LD);

  short8 ones;
#pragma unroll
  for (int i = 0; i < 8; ++i) ones[i] = (short)ONEBF;

  f32x4 Oa[2][2], Osum[2];
#pragma unroll
  for (int mt = 0; mt < 2; ++mt) {
    Osum[mt] = (f32x4){0.f, 0.f, 0.f, 0.f};
#pragma unroll
    for (int dt = 0; dt < 2; ++dt) Oa[mt][dt] = (f32x4){0.f, 0.f, 0.f, 0.f};
  }

  const int jmax    = min(N_, (nn + 63) & ~63);
  const int jmax128 = (jmax + 127) & ~127;   // padded chunks are exact zeros

  // fragment base pointers
  const unsigned short* kfb =
      qkv + (size_t)(b * N_ + c) * QKV_LD + 512 + h * DH_ + q4 * 8;   // + (j0+nt*16)*LD
  const unsigned short* vfb =
      vtb + ((size_t)(b * 512 + h * DH_ + c)) * 512 + q4 * 8;         // + dt*16*512 + j0+js*32
  const unsigned char* cb2 = code + (size_t)(b * N_ + i0 + w * 32) * N_ + c * 4;

  short8 Ka[4], Va[4], Kb[4], Vb[4];
  unsigned int Da[8], Db[8];

#define PREF(KF, VF, DR, J0)                                                   \
  {                                                                            \
    _Pragma("unroll")                                                          \
    for (int nt = 0; nt < 4; ++nt)                                             \
      KF[nt] = *(const short8*)(kfb + (size_t)((J0) + nt * 16) * QKV_LD);      \
    _Pragma("unroll")                                                          \
    for (int jd = 0; jd < 4; ++jd)                                             \
      VF[jd] = *(const short8*)(vfb + (size_t)(jd & 1) * 16 * 512 + (J0) +     \
                                (jd >> 1) * 32);                               \
    _Pragma("unroll")                                                          \
    for (int it = 0; it < 8; ++it)                                             \
      DR[it] = *(const unsigned int*)(cb2 + (size_t)(it * 4 + q4) * N_ + (J0));\
  }

#define CHUNK(KF, VF, DR, PH)                                                  \
  {                                                                            \
    f32x4 S[2][4];                                                             \
    _Pragma("unroll")                                                          \
    for (int nt = 0; nt < 4; ++nt)                                             \
      _Pragma("unroll")                                                        \
      for (int mt = 0; mt < 2; ++mt)                                           \
        S[mt][nt] = __builtin_amdgcn_mfma_f32_16x16x32_bf16(                   \
            Qf[mt], KF[nt], (f32x4){0.f, 0.f, 0.f, 0.f}, 0, 0, 0);             \
    _Pragma("unroll")                                                          \
    for (int it = 0; it < 8; ++it) {                                           \
      unsigned int cw = DR[it];                                                \
      unsigned int e0 = sbxw[w][cw & 15], e1 = sbxw[w][(cw >> 8) & 15];        \
      unsigned int e2 = sbxw[w][(cw >> 16) & 15], e3 = sbxw[w][cw >> 24];      \
      unsigned int* pw = (unsigned int*)&PB[w][PH][it * 4 + q4][c * 4];        \
      pw[0] = e0 | (e1 << 16);                                                 \
      pw[1] = e2 | (e3 << 16);                                                 \
    }                                                                          \
    _Pragma("unroll")                                                          \
    for (int mt = 0; mt < 2; ++mt) {                                           \
      _Pragma("unroll")                                                        \
      for (int r = 0; r < 4; ++r) {                                            \
        const int row = mt * 16 + q4 * 4 + r;                                  \
        _Pragma("unroll")                                                      \
        for (int nt = 0; nt < 4; ++nt) {                                       \
          float p = __expf(fminf(                                              \
              S[mt][nt][r] + bf2f(PB[w][PH][row][nt * 16 + c]), 60.f));        \
          PB[w][PH][row][nt * 16 + c] = f2bf(p);                               \
        }                                                                      \
      }                                                                        \
    }                                                                          \
    _Pragma("unroll")                                                          \
    for (int js = 0; js < 2; ++js) {                                           \
      short8 Pa[2];                                                            \
      _Pragma("unroll")                                                        \
      for (int mt = 0; mt < 2; ++mt)                                           \
        Pa[mt] = *(const short8*)&PB[w][PH][mt * 16 + c][js * 32 + q4 * 8];    \
      _Pragma("unroll")                                                        \
      for (int mt = 0; mt < 2; ++mt) {                                         \
        _Pragma("unroll")                                                      \
        for (int dt = 0; dt < 2; ++dt)                                         \
          Oa[mt][dt] = __builtin_amdgcn_mfma_f32_16x16x32_bf16(                \
              Pa[mt], VF[js * 2 + dt], Oa[mt][dt], 0, 0, 0);                   \
        Osum[mt] = __builtin_amdgcn_mfma_f32_16x16x32_bf16(                    \
            Pa[mt], ones, Osum[mt], 0, 0, 0);                                  \
      }                                                                        \
    }                                                                          \
  }

  PREF(Ka, Va, Da, 0)
  PREF(Kb, Vb, Db, 64)

  for (int j0 = 0; j0 < jmax128; j0 += 128) {
    CHUNK(Ka, Va, Da, 0)
    if (j0 + 128 < jmax128) PREF(Ka, Va, Da, j0 + 128)
    CHUNK(Kb, Vb, Db, 1)
    if (j0 + 192 < jmax128) PREF(Kb, Vb, Db, j0 + 192)
  }
#undef PREF
#undef CHUNK

  // ---- epilogue
#pragma unroll
  for (int mt = 0; mt < 2; ++mt)
#pragma unroll
    for (int r = 0; r < 4; ++r) {
      float inv = 1.f / Osum[mt][r];
      int i = i0 + w * 32 + mt * 16 + q4 * 4 + r;
      unsigned short* op = o + (size_t)(b * N_ + i) * F_ + h * DH_;
#pragma unroll
      for (int dt = 0; dt < 2; ++dt)
        op[dt * 16 + c] = f2bf(Oa[mt][dt][r] * inv);
    }
}

// ---------------------------------------------------------------- add + LN
__device__ __forceinline__ float block_reduce_sum(float val, float* sbuf) {
#pragma unroll
  for (int off = 32; off > 0; off >>= 1) val += __shfl_xor(val, off, 64);
  int wid = threadIdx.x >> 6;
  if ((threadIdx.x & 63) == 0) sbuf[wid] = val;
  __syncthreads();
  val = sbuf[0] + sbuf[1] + sbuf[2] + sbuf[3];
  __syncthreads();
  return val;
}

__global__ __launch_bounds__(256) void add_ln_kernel(
    float* __restrict__ x, const unsigned short* __restrict__ t,
    const float* __restrict__ gam, const float* __restrict__ bet,
    unsigned short* __restrict__ xb, const int* __restrict__ num_nodes)
{
  int row = blockIdx.x;
  {
    int bb = row >> 9;
    int nnr = (num_nodes[bb] + 127) & ~127;
    if ((row & 511) >= nnr) return;
  }
  __shared__ float sbuf[4];
  int f0 = threadIdx.x, f1 = f0 + 256;
  size_t base = (size_t)row * F_;
  float v0 = x[base + f0] + bf2f(t[base + f0]);
  float v1 = x[base + f1] + bf2f(t[base + f1]);
  float mean = block_reduce_sum(v0 + v1, sbuf) * (1.f / 512.f);
  float e0 = v0 - mean, e1 = v1 - mean;
  float var = block_reduce_sum(e0 * e0 + e1 * e1, sbuf) * (1.f / 512.f);
  float rstd = rsqrtf(var + 1e-5f);
  float o0 = e0 * rstd * gam[f0] + bet[f0];
  float o1 = e1 * rstd * gam[f1] + bet[f1];
  x[base + f0] = o0;
  x[base + f1] = o1;
  xb[base + f0] = f2bf(o0);
  xb[base + f1] = f2bf(o1);
}

// ---------------------------------------------------------------- pool (2-stage)
__global__ __launch_bounds__(256) void pool_partial_kernel(
    const float* __restrict__ x, const int* __restrict__ num_nodes,
    const float* __restrict__ clf_w, float* __restrict__ part)
{
  __shared__ float sbuf[4];
  int b = blockIdx.x, s = blockIdx.y, t = threadIdx.x;
  int nn = num_nodes[b];
  const float* xp = x + (size_t)b * N_ * F_;
  float a0 = 0.f, a1 = 0.f;
  for (int n = s; n < nn; n += 32) {
    a0 += xp[(size_t)n * F_ + t];
    a1 += xp[(size_t)n * F_ + t + 256];
  }
  float partial = a0 * clf_w[t] + a1 * clf_w[t + 256];
  float tot = block_reduce_sum(partial, sbuf);
  if (t == 0) part[b * 32 + s] = tot;
}

__global__ __launch_bounds__(64) void pool_final_kernel(
    const float* __restrict__ part, const int* __restrict__ num_nodes,
    const float* __restrict__ clf_b, float* __restrict__ out)
{
  int b = threadIdx.x;
  if (b >= B_) return;
  float tot = 0.f;
#pragma unroll
  for (int s = 0; s < 32; ++s) tot += part[b * 32 + s];
  float logit = tot / (float)num_nodes[b] + clf_b[0];
  out[b] = 1.f / (1.f + __expf(-logit));
}

// ---------------------------------------------------------------- launch
extern "C" void kernel_launch(void* const* d_in, const int* in_sizes, int n_in,
                              void* d_out, int out_size, void* d_ws, size_t ws_size,
                              hipStream_t stream)
{
  (void)in_sizes; (void)n_in; (void)out_size; (void)ws_size;

  const float* nfeats    = (const float*)d_in[0];
  const int*   degrees   = (const int*)d_in[1];
  const int*   dist_idx  = (const int*)d_in[2];
  const int*   num_nodes = (const int*)d_in[3];
  const float* deg_in    = (const float*)d_in[4];
  const float* deg_out   = (const float*)d_in[5];
  const float* semb      = (const float*)d_in[6];
  const float* Wq = (const float*)d_in[7];  const float* bq = (const float*)d_in[8];
  const float* Wk = (const float*)d_in[9];  const float* bk = (const float*)d_in[10];
  const float* Wv = (const float*)d_in[11]; const float* bv = (const float*)d_in[12];
  const float* Wo = (const float*)d_in[13]; const float* bo = (const float*)d_in[14];
  const float* ln1s = (const float*)d_in[15]; const float* ln1b = (const float*)d_in[16];
  const float* W1 = (const float*)d_in[17]; const float* b1 = (const float*)d_in[18];
  const float* W2 = (const float*)d_in[19]; const float* b2 = (const float*)d_in[20];
  const float* ln2s = (const float*)d_in[21]; const float* ln2b = (const float*)d_in[22];
  const float* clfw = (const float*)d_in[23]; const float* clfb = (const float*)d_in[24];
  float* out = (float*)d_out;

  const int M = B_ * N_;            // 8192
  char* p = (char*)d_ws;
  auto alloc = [&](size_t bytes) { char* r = p; p += (bytes + 255) & ~255ULL; return r; };

  float*          x     = (float*)alloc((size_t)M * F_ * 4);              // 16 MB
  unsigned short* xb    = (unsigned short*)alloc((size_t)M * F_ * 2);     // 8 MB
  char*           R     = alloc((size_t)M * QKV_LD * 4);                  // 50 MB
  unsigned short* ob    = (unsigned short*)alloc((size_t)M * F_ * 2);     // 8 MB
  unsigned short* vtb   = (unsigned short*)alloc((size_t)M * F_ * 2);     // 8 MB V^T
  unsigned short* wQKVt = (unsigned short*)alloc((size_t)L_ * QKV_LD * F_ * 2);
  unsigned short* wOt   = (unsigned short*)alloc((size_t)L_ * F_ * F_ * 2);
  unsigned short* wW1t  = (unsigned short*)alloc((size_t)L_ * HID_ * F_ * 2);
  unsigned short* wW2t  = (unsigned short*)alloc((size_t)L_ * F_ * HID_ * 2);
  float*          bqkv  = (float*)alloc((size_t)L_ * QKV_LD * 4);
  float*          part  = (float*)alloc((size_t)B_ * 32 * 4);
  unsigned char*  code  = (unsigned char*)alloc((size_t)B_ * N_ * N_);    // 4 MB

  unsigned short* qkvb = (unsigned short*)R;                 // bf16 [M][1536]
  unsigned short* tbh  = (unsigned short*)R;                 // bf16 [M][512] (reuse)
  unsigned short* hb   = (unsigned short*)(R + (size_t)M * F_ * 4);  // bf16 [M][2048]

  const float scale = 0.17677669529663687f;  // 1/sqrt(32)

  dim3 tb32(32, 8);
  tconv4_kernel<<<dim3(16, 16, 4 * L_), tb32, 0, stream>>>(
      Wq, Wk, Wv, Wo, wQKVt, wOt);
  tconv_kernel<<<dim3(64, 16, L_), tb32, 0, stream>>>(W1, wW1t, F_, HID_,
      (size_t)F_ * HID_, (size_t)F_ * HID_, 0);
  tconv_kernel<<<dim3(16, 64, L_), tb32, 0, stream>>>(W2, wW2t, HID_, F_,
      (size_t)F_ * HID_, (size_t)F_ * HID_, 0);
  biasqkv_kernel<<<dim3((L_ * QKV_LD + 255) / 256), 256, 0, stream>>>(bq, bk, bv, bqkv);
  packcode_kernel<<<dim3((B_ * N_ * N_) / 4 / 256), 256, 0, stream>>>(
      dist_idx, num_nodes, code);

  embed_kernel<<<dim3((M * F_) / 4 / 256), 256, 0, stream>>>(
      nfeats, degrees, num_nodes, deg_in, deg_out, x, xb);

  for (int l = 0; l < L_; ++l) {
    const unsigned short* wqkv_l = wQKVt + (size_t)l * QKV_LD * F_;
    const unsigned short* wo_l   = wOt   + (size_t)l * F_ * F_;
    const unsigned short* w1_l   = wW1t  + (size_t)l * HID_ * F_;
    const unsigned short* w2_l   = wW2t  + (size_t)l * F_ * HID_;

    mfma_gemm_kernel<<<dim3(M / 128, QKV_LD / 128), 256, 0, stream>>>(
        xb, wqkv_l, bqkv + l * QKV_LD, nullptr, qkvb, vtb, F_, QKV_LD, scale, 2, num_nodes);

    attn_kernel<<<dim3(H_, N_ / 128, B_), 256, 0, stream>>>(
        qkvb, vtb, code, semb, num_nodes, ob);

    mfma_gemm64_kernel<<<dim3(M / 64, F_ / 128), 256, 0, stream>>>(
        ob, wo_l, bo + l * F_, tbh, F_, F_, num_nodes);
    add_ln_kernel<<<dim3(M), 256, 0, stream>>>(x, tbh, ln1s + l * F_, ln1b + l * F_, xb, num_nodes);

    mfma_gemm_kernel<<<dim3(M / 128, HID_ / 128), 256, 0, stream>>>(
        xb, w1_l, b1 + l * HID_, nullptr, hb, nullptr, F_, HID_, 1.f, 1, num_nodes);
    mfma_gemm64_kernel<<<dim3(M / 64, F_ / 128), 256, 0, stream>>>(
        hb, w2_l, b2 + l * F_, tbh, HID_, F_, num_nodes);
    add_ln_kernel<<<dim3(M), 256, 0, stream>>>(x, tbh, ln2s + l * F_, ln2b + l * F_, xb, num_nodes);
  }

  pool_partial_kernel<<<dim3(B_, 32), 256, 0, stream>>>(x, num_nodes, clfw, part);
  pool_final_kernel<<<dim3(1), 64, 0, stream>>>(part, num_nodes, clfb, out);
}